// Round 1
// baseline (14425.060 us; speedup 1.0000x reference)
//
#include <hip/hip_runtime.h>
#include <stdint.h>

// Recursive Gaussian LSTM, persistent cooperative kernel.
// B=64, T=512, D=256, HS=256. 32 WGs x 256 threads, each WG owns 8 "units"
// (columns) of every per-step GEMM. Weights live in registers as MFMA
// B-fragments (bf16). Per step: phase A (gates GEMM K=512 over [x_t|h]),
// in-WG LDS transpose + activations, global exchange of pre_h/pre_c,
// spin barrier, phase B (reparam GEMMs K=256), sampling epilogue, writes
// h to the parity-flipped exchange buffer, spin barrier.
// c-state stays in registers (fp32) the whole run; h exchanged as bf16.

#define NWG 32
#define UPW 8   // units per WG
#define T_STEPS 512
#define STRIDE_OUT 8388608  // B*T*HS

typedef float floatx4 __attribute__((ext_vector_type(4)));
typedef short bfx8 __attribute__((ext_vector_type(8)));

__device__ inline short f2bf(float f) {
  union { float f; uint32_t u; } v; v.f = f;
  uint32_t r = v.u + 0x7fffu + ((v.u >> 16) & 1u);  // RNE
  return (short)(r >> 16);
}
__device__ inline float sigm(float x) { return 1.f / (1.f + __expf(-x)); }
__device__ inline float tanhfast(float x) {
  float e = __expf(2.f * x);
  return 1.f - 2.f / (e + 1.f);   // saturates correctly at +/-inf
}
__device__ inline float softplusf(float x) {
  return (x > 15.f) ? x : log1pf(__expf(x));
}

// slot-per-WG sense barrier: release own slot to epoch, wave0 spins on all.
__device__ inline void gbar(int* slots, int wg, int ep) {
  __syncthreads();  // all WG writes done before release
  if (threadIdx.x == 0)
    __hip_atomic_store(slots + wg * 16, ep, __ATOMIC_RELEASE, __HIP_MEMORY_SCOPE_AGENT);
  if (threadIdx.x < 64) {
    int lane = threadIdx.x;
    bool need = lane < NWG;
    int v;
    do {
      v = need ? __hip_atomic_load(slots + lane * 16, __ATOMIC_ACQUIRE, __HIP_MEMORY_SCOPE_AGENT)
               : ep;
      if (v < ep) __builtin_amdgcn_s_sleep(1);
    } while (__any(v < ep));
  }
  __syncthreads();
  __threadfence();  // acquire for all threads of the WG
}

__global__ __launch_bounds__(256, 1)
void glstm_kernel(const float* __restrict__ x,
                  const float* __restrict__ Wih,
                  const float* __restrict__ Whh,
                  const float* __restrict__ bias,
                  const float* __restrict__ Hrep,
                  const float* __restrict__ Crep,
                  const float* __restrict__ eps_h,
                  const float* __restrict__ eps_c,
                  float* __restrict__ out,
                  int* __restrict__ slots,
                  short* __restrict__ ht0,
                  short* __restrict__ ht1,
                  short* __restrict__ preh,
                  short* __restrict__ prec) {
  const int wg   = blockIdx.x;
  const int tid  = threadIdx.x;
  const int wave = tid >> 6;     // phase A: gate type i/f/g/o; phase B: mu_h/std_h/mu_c/std_c
  const int l    = tid & 63;
  const int n    = l & 15;       // MFMA col within n-tile / A-frag row (batch within M-tile)
  const int quad = l >> 4;
  const bool act = (n < UPW);    // only 8 of 16 n-lanes carry real columns
  const int s    = wg * UPW + (act ? n : 0);   // global unit id [0,256)

  __shared__ float xch[4][64][9];  // [type][batch][unit] transpose buffer (9.2 KB)

  // ---------------- one-time init: B-fragments into registers ----------------
  // B-frag layout: lane holds B[k = kt*32 + quad*8 + j][col = n-tile col]
  bfx8 Bg[16];   // gates: K=512 (k<256 -> W_ih, else W_hh), col = wave*256 + s
  bfx8 Br[8];    // reparam: K=256, col = (wave&1)*256 + s in Hrep (wave<2) / Crep
  {
    const int gcol = wave * 256 + s;
    #pragma unroll
    for (int kt = 0; kt < 16; ++kt) {
      bfx8 r;
      #pragma unroll
      for (int j = 0; j < 8; ++j) {
        int k = kt * 32 + quad * 8 + j;
        float v = 0.f;
        if (act) v = (k < 256) ? Wih[k * 1024 + gcol] : Whh[(k - 256) * 1024 + gcol];
        r[j] = f2bf(v);
      }
      Bg[kt] = r;
    }
    const float* R = (wave < 2) ? Hrep : Crep;
    const int rcol = (wave & 1) * 256 + s;
    #pragma unroll
    for (int kt = 0; kt < 8; ++kt) {
      bfx8 r;
      #pragma unroll
      for (int j = 0; j < 8; ++j) {
        int k = kt * 32 + quad * 8 + j;
        float v = act ? R[k * 512 + rcol] : 0.f;
        r[j] = f2bf(v);
      }
      Br[kt] = r;
    }
  }
  float bi = 0.f, bfv = 0.f, bgv = 0.f, bov = 0.f;
  if (act) { bi = bias[s]; bfv = bias[256 + s]; bgv = bias[512 + s]; bov = bias[768 + s]; }
  float c_reg[4] = {0.f, 0.f, 0.f, 0.f};  // c-state for (b = wave*16 + quad*4 + r, unit s)

  #pragma unroll 1
  for (int t = 0; t < T_STEPS; ++t) {
    const short* htr = (t & 1) ? ht1 : ht0;   // h(t-1), zeros at t=0
    short* htw       = (t & 1) ? ht0 : ht1;   // h(t)

    // ---------------- phase A: gates = [x_t | h] @ [Wih; Whh] ----------------
    floatx4 acc[4];
    #pragma unroll
    for (int mt = 0; mt < 4; ++mt) acc[mt] = 0.f;
    #pragma unroll
    for (int kt = 0; kt < 16; ++kt) {
      bfx8 a[4];
      #pragma unroll
      for (int mt = 0; mt < 4; ++mt) {
        int b = mt * 16 + n;   // A-frag row m = lane&15
        if (kt < 8) {
          const floatx4* px = (const floatx4*)(x + ((size_t)(b * 512 + t)) * 256 + kt * 32 + quad * 8);
          floatx4 lo = px[0], hi = px[1];
          bfx8 av;
          av[0] = f2bf(lo[0]); av[1] = f2bf(lo[1]); av[2] = f2bf(lo[2]); av[3] = f2bf(lo[3]);
          av[4] = f2bf(hi[0]); av[5] = f2bf(hi[1]); av[6] = f2bf(hi[2]); av[7] = f2bf(hi[3]);
          a[mt] = av;
        } else {
          a[mt] = *(const bfx8*)(htr + b * 256 + (kt - 8) * 32 + quad * 8);
        }
      }
      #pragma unroll
      for (int mt = 0; mt < 4; ++mt)
        acc[mt] = __builtin_amdgcn_mfma_f32_16x16x32_bf16(a[mt], Bg[kt], acc[mt], 0, 0, 0);
    }
    // transpose via LDS: D layout row=quad*4+reg, col=n
    if (act) {
      #pragma unroll
      for (int mt = 0; mt < 4; ++mt)
        #pragma unroll
        for (int r = 0; r < 4; ++r)
          xch[wave][mt * 16 + quad * 4 + r][n] = acc[mt][r];
    }
    __syncthreads();
    // activations + pre_c / pre_h, write exchange bufs (bf16)
    if (act) {
      #pragma unroll
      for (int r = 0; r < 4; ++r) {
        int b = wave * 16 + quad * 4 + r;
        float gi = sigm(xch[0][b][n] + bi);
        float gf = sigm(xch[1][b][n] + bfv);
        float gg = tanhfast(xch[2][b][n] + bgv);
        float go = sigm(xch[3][b][n] + bov);
        float pc = gf * c_reg[r] + gi * gg;
        float ph = go * tanhfast(c_reg[r]);   // OLD c
        preh[b * 256 + s] = f2bf(ph);
        prec[b * 256 + s] = f2bf(pc);
      }
    }
    gbar(slots, wg, 2 * t + 1);

    // ---------------- phase B: reparam GEMMs ----------------
    const short* pA = (wave < 2) ? preh : prec;
    floatx4 racc[4];
    #pragma unroll
    for (int mt = 0; mt < 4; ++mt) racc[mt] = 0.f;
    #pragma unroll
    for (int kt = 0; kt < 8; ++kt) {
      bfx8 a[4];
      #pragma unroll
      for (int mt = 0; mt < 4; ++mt)
        a[mt] = *(const bfx8*)(pA + (mt * 16 + n) * 256 + kt * 32 + quad * 8);
      #pragma unroll
      for (int mt = 0; mt < 4; ++mt)
        racc[mt] = __builtin_amdgcn_mfma_f32_16x16x32_bf16(a[mt], Br[kt], racc[mt], 0, 0, 0);
    }
    if (act) {
      #pragma unroll
      for (int mt = 0; mt < 4; ++mt)
        #pragma unroll
        for (int r = 0; r < 4; ++r)
          xch[wave][mt * 16 + quad * 4 + r][n] = racc[mt][r];
    }
    __syncthreads();
    // sampling epilogue + all outputs
    if (act) {
      #pragma unroll
      for (int r = 0; r < 4; ++r) {
        int b = wave * 16 + quad * 4 + r;
        float mh  = fminf(fmaxf(xch[0][b][n], 1e-6f), 1e6f);
        float sh  = fmaxf(softplusf(xch[1][b][n]), 1e-6f);
        float mc  = fminf(fmaxf(xch[2][b][n], 1e-6f), 1e6f);
        float scv = fmaxf(softplusf(xch[3][b][n]), 1e-6f);
        float eh = eps_h[((size_t)t * 64 + b) * 256 + s];
        float ec = eps_c[((size_t)t * 64 + b) * 256 + s];
        float hn = mh + eh * sh;
        float cn = mc + ec * scv;
        c_reg[r] = cn;
        htw[b * 256 + s] = f2bf(hn);
        size_t o = ((size_t)b * 512 + t) * 256 + s;
        out[o] = hn;
        out[(size_t)STRIDE_OUT + o] = cn;
        out[2 * (size_t)STRIDE_OUT + o] = mh;
        out[3 * (size_t)STRIDE_OUT + o] = sh;
        out[4 * (size_t)STRIDE_OUT + o] = mc;
        out[5 * (size_t)STRIDE_OUT + o] = scv;
        if (t == T_STEPS - 1) {
          out[6 * (size_t)STRIDE_OUT + b * 256 + s] = hn;
          out[6 * (size_t)STRIDE_OUT + 16384 + b * 256 + s] = cn;
        }
      }
    }
    gbar(slots, wg, 2 * t + 2);
  }
}

extern "C" void kernel_launch(void* const* d_in, const int* in_sizes, int n_in,
                              void* d_out, int out_size, void* d_ws, size_t ws_size,
                              hipStream_t stream) {
  const float* x    = (const float*)d_in[0];
  const float* Wih  = (const float*)d_in[1];
  const float* Whh  = (const float*)d_in[2];
  const float* bias = (const float*)d_in[3];
  const float* Hrep = (const float*)d_in[4];
  const float* Crep = (const float*)d_in[5];
  const float* eps_h = (const float*)d_in[6];
  const float* eps_c = (const float*)d_in[7];
  float* out = (float*)d_out;

  char* ws = (char*)d_ws;
  int*   slots = (int*)ws;                          // 32 x 64B slots
  short* ht0   = (short*)(ws + 2048);               // h exchange, parity 0 (zeros at t=0)
  short* ht1   = (short*)(ws + 2048 + 32768);       // h exchange, parity 1
  short* preh  = (short*)(ws + 2048 + 2 * 32768);   // pre_h exchange
  short* prec  = (short*)(ws + 2048 + 3 * 32768);   // pre_c exchange
  // zero barriers + h(0); runs inside capture on every launch
  hipMemsetAsync(d_ws, 0, 2048 + 4 * 32768, stream);

  glstm_kernel<<<dim3(NWG), dim3(256), 0, stream>>>(
      x, Wih, Whh, bias, Hrep, Crep, eps_h, eps_c, out,
      slots, ht0, ht1, preh, prec);
}